// Round 1
// baseline (4677.797 us; speedup 1.0000x reference)
//
#include <hip/hip_runtime.h>
#include <hip/hip_fp16.h>
#include <cstddef>

// FDRNN: fuzzy -> FC(200->1024->1024->1024->128) -> 2-layer tanh RNN (H=512)
// B=64, S=512 -> 32768 rows.
//
// R6: RNN restructured. R5 streamed 176KB of W per step per CU (per-CU L2
// fill-rate bound, ~6000 cyc/step, 64 CUs active). Now each batch's 512
// outputs are split across 2 blocks (128 blocks): per-thread W slice =
// 256 fp16 = 128 VGPRs -> W fully register-resident, zero per-step W
// traffic. Per-step cross-block h-slice exchange via agent-scope (sc1,
// L3-coherent) atomics + monotonic flags; wave 1 spins+fetches the
// partner slice. Model: ~700 cyc compute + ~1400 cyc exchange per step.

typedef _Float16 half8 __attribute__((ext_vector_type(8)));
typedef float f32x4 __attribute__((ext_vector_type(4)));
typedef _Float16 v2h __attribute__((ext_vector_type(2)));

__device__ __forceinline__ void gld_lds16(const void* g, void* lds) {
  __builtin_amdgcn_global_load_lds(
      (const __attribute__((address_space(1))) unsigned int*)g,
      (__attribute__((address_space(3))) unsigned int*)lds, 16, 0, 0);
}

// ---------------- fuzzy (fp16 out, K padded 200->256) ----------------
__global__ void fuzzy16(const float* __restrict__ x, const float* __restrict__ fp,
                        _Float16* __restrict__ z, int nrows) {
  int idx = blockIdx.x * blockDim.x + threadIdx.x;
  if (idx >= nrows * 256) return;
  int r = idx >> 8;
  int f = idx & 255;
  float v = 0.f;
  if (f < 200) {
    int i = f % 50;
    float xv = x[r * 50 + i];
    float mu = fp[2 * f];
    float sg = fp[2 * f + 1];
    float d = xv - mu;
    v = expf(-(d * d) / sg);
  }
  z[idx] = (_Float16)v;
}

// ---------------- weight fp32 -> fp16 (with optional K zero-pad) -------------
__global__ void cvt_w16(const float* __restrict__ W, _Float16* __restrict__ O,
                        int rows, int kin, int kpad) {
  int idx = blockIdx.x * blockDim.x + threadIdx.x;
  if (idx >= rows * kpad) return;
  int r = idx / kpad;
  int k = idx - r * kpad;
  O[idx] = (k < kin) ? (_Float16)W[(size_t)r * kin + k] : (_Float16)0.f;
}

// ---------------- MFMA fp16 GEMM: C16[M][N] = A16[M][K] @ W16[N][K]^T + b ----
__global__ __launch_bounds__(256) void gemm16(
    const _Float16* __restrict__ A, const _Float16* __restrict__ W,
    const float* __restrict__ b1, const float* __restrict__ b2,
    _Float16* __restrict__ C, int M, int N, int K) {
  __shared__ _Float16 As[128 * 32];
  __shared__ _Float16 Bs[128 * 32];
  const int tid = threadIdx.x;
  const int bm = blockIdx.y * 128;
  const int bn = blockIdx.x * 128;
  const int lane = tid & 63;
  const int wv = tid >> 6;
  const int wm = (wv >> 1) * 64;
  const int wn = (wv & 1) * 64;
  const int frow = lane & 15;
  const int fk = (lane >> 4) * 8;

  const int srow = tid >> 2;
  const int scol = (tid & 3) * 16;  // bytes
  const char* gA = (const char*)(A + (size_t)(bm + srow) * K) + scol;
  const char* gB = (const char*)(W + (size_t)(bn + srow) * K) + scol;
  const size_t rowstep = (size_t)64 * K * 2;
  char* lA = (char*)As + tid * 16;
  char* lB = (char*)Bs + tid * 16;

  f32x4 acc[4][4] = {};

  for (int k0 = 0; k0 < K; k0 += 32) {
    gld_lds16(gA, lA);
    gld_lds16(gA + rowstep, lA + 4096);
    gld_lds16(gB, lB);
    gld_lds16(gB + rowstep, lB + 4096);
    gA += 64;
    gB += 64;
    __syncthreads();
    half8 af[4], bf[4];
#pragma unroll
    for (int i = 0; i < 4; i++) {
      af[i] = *(const half8*)(As + (wm + i * 16 + frow) * 32 + fk);
      bf[i] = *(const half8*)(Bs + (wn + i * 16 + frow) * 32 + fk);
    }
#pragma unroll
    for (int i = 0; i < 4; i++)
#pragma unroll
      for (int j = 0; j < 4; j++)
        acc[i][j] = __builtin_amdgcn_mfma_f32_16x16x32_f16(af[i], bf[j], acc[i][j], 0, 0, 0);
    __syncthreads();
  }

  float bias[4];
#pragma unroll
  for (int j = 0; j < 4; j++) {
    int col = bn + wn + j * 16 + frow;
    bias[j] = b1[col] + (b2 ? b2[col] : 0.f);
  }
  const int r0 = (lane >> 4) * 4;
#pragma unroll
  for (int i = 0; i < 4; i++) {
#pragma unroll
    for (int r = 0; r < 4; r++) {
      int row = bm + wm + i * 16 + r0 + r;
      _Float16* Cp = C + (size_t)row * N + bn + wn + frow;
#pragma unroll
      for (int j = 0; j < 4; j++)
        Cp[j * 16] = (_Float16)(acc[i][j][r] + bias[j]);
    }
  }
}

// ---------------- RNN weight pack (fp32 -> fp16, 16B groups) ----------------
// QW[j4*512 + o] = 8 fp16 = w_hh[o][8*j4 .. 8*j4+7]
__global__ void pack_whh_fp16(const float* __restrict__ W, float4* __restrict__ QW) {
  int idx = blockIdx.x * blockDim.x + threadIdx.x;
  if (idx >= 32768) return;
  int j4 = idx >> 9;
  int o = idx & 511;
  const float* src = W + (size_t)o * 512 + j4 * 8;
  __align__(16) __half2 p[4];
#pragma unroll
  for (int k = 0; k < 4; k++)
    p[k] = __halves2half2(__float2half(src[2 * k]), __float2half(src[2 * k + 1]));
  QW[idx] = *(const float4*)p;
}

__device__ __forceinline__ float dot2acc(float wbits, float hbits, float acc) {
#if __has_builtin(__builtin_amdgcn_fdot2)
  return __builtin_amdgcn_fdot2(__builtin_bit_cast(v2h, wbits),
                                __builtin_bit_cast(v2h, hbits), acc, false);
#else
  float2 wf = __half22float2(__builtin_bit_cast(__half2, wbits));
  float2 hf = __half22float2(__builtin_bit_cast(__half2, hbits));
  return fmaf(wf.x, hf.x, fmaf(wf.y, hf.y, acc));
#endif
}

// ---------------- RNN: 2 blocks per batch, W register-resident ----------------
// Block (s = bid>>6, b = bid&63) owns outputs o in [s*256, s*256+256).
// Thread (ol = tid>>1, jh = tid&1): W[o][jh*256 .. +256) = 32 float4 in VGPRs.
// Per step: dot over own j-half, shfl_xor(1) pair-combine, tanh; own slice
// stored to xchg via agent-scope atomics (sc1 -> L3, coherent across XCDs);
// flag (monotonic t+1) released after __syncthreads (which drains vmcnt, so
// all lanes' slice stores are at the coherence point first). Wave 1 spins on
// the partner flag and fetches the partner slice into LDS.
__global__ __launch_bounds__(512, 2) void rnn_split_k(
    const _Float16* __restrict__ pre,   // [64][512][512] fp16, biases folded
    const float4* __restrict__ QW,      // packed fp16 w_hh [64 j4][512 o]
    float* __restrict__ out32,          // nullable: final fp32 output
    _Float16* __restrict__ xchg,        // [64][512][512] fp16 h (output + exchange)
    unsigned int* __restrict__ flags) { // [64][2] monotonic step counters
  const int bid = blockIdx.x;
  const int s = bid >> 6;
  const int b = bid & 63;
  const int tid = threadIdx.x;
  const int ol = tid >> 1;
  const int jh = tid & 1;
  const int o = (s << 8) + ol;
  const int wv = tid >> 6;

  __shared__ __align__(16) __half hsh[512];

  const float4* qrow = QW + o;
  float4 w[32];
#pragma unroll
  for (int k = 0; k < 32; k++) w[k] = qrow[(size_t)((jh << 5) + k) << 9];

  if (tid < 256) ((float*)hsh)[tid] = 0.f;
  __syncthreads();

  const _Float16* preb = pre + (size_t)b * 262144;
  _Float16* xb = xchg + (size_t)b * 262144;
  float* ob = out32 ? out32 + (size_t)b * 262144 : nullptr;
  unsigned int* myflag = flags + (b << 1) + s;
  unsigned int* pflag = flags + (b << 1) + (s ^ 1);
  const float4* hs4 = (const float4*)hsh;
  const int hbase = jh << 5;

  for (int t = 0; t < 512; t++) {
    float a0 = (jh == 0) ? (float)preb[(t << 9) + o] : 0.f;
    float a1 = 0.f, a2 = 0.f, a3 = 0.f;
#pragma unroll
    for (int k = 0; k < 32; k++) {
      float4 hq = hs4[hbase + k];
      a0 = dot2acc(w[k].x, hq.x, a0);
      a1 = dot2acc(w[k].y, hq.y, a1);
      a2 = dot2acc(w[k].z, hq.z, a2);
      a3 = dot2acc(w[k].w, hq.w, a3);
    }
    float v = (a0 + a1) + (a2 + a3);
    v += __shfl_xor(v, 1);
    float hn = tanhf(v);
    __half hh = __float2half(hn);
    float hn2 = __shfl_down(hn, 2);  // lane 4m gets lane 4m+2's value (odd o)
    if ((tid & 3) == 0) {
      __half2 pr = __halves2half2(hh, __float2half(hn2));
      unsigned int val = __builtin_bit_cast(unsigned int, pr);
      unsigned int* xrow = (unsigned int*)(xb + ((size_t)t << 9));
      __hip_atomic_store(xrow + (s << 7) + (tid >> 2), val, __ATOMIC_RELAXED,
                         __HIP_MEMORY_SCOPE_AGENT);
    }
    if (ob && jh == 0) ob[(t << 9) + o] = hn;
    __syncthreads();  // [A] h_{t-1} reads done; slice stores drained (vmcnt 0)
    if (jh == 0) hsh[o] = hh;  // own half -> h_t
    if (tid == 0)
      __hip_atomic_store(myflag, (unsigned int)(t + 1), __ATOMIC_RELEASE,
                         __HIP_MEMORY_SCOPE_AGENT);
    if (t < 511 && wv == 1) {
      const unsigned int target = (unsigned int)(t + 1);
      while (__hip_atomic_load(pflag, __ATOMIC_RELAXED, __HIP_MEMORY_SCOPE_AGENT) <
             target) {
      }
      asm volatile("" ::: "memory");  // keep data load after spin exit
      const unsigned long long* prow =
          (const unsigned long long*)(xb + ((size_t)t << 9)) + ((s ^ 1) << 6);
      unsigned long long dv = __hip_atomic_load(prow + (tid & 63), __ATOMIC_RELAXED,
                                                __HIP_MEMORY_SCOPE_AGENT);
      ((unsigned long long*)hsh)[((s ^ 1) << 6) + (tid & 63)] = dv;
    }
    __syncthreads();  // [B] hsh = full h_t
  }
}

extern "C" void kernel_launch(void* const* d_in, const int* in_sizes, int n_in,
                              void* d_out, int out_size, void* d_ws, size_t ws_size,
                              hipStream_t stream) {
  const float* x     = (const float*)d_in[0];
  const float* fp    = (const float*)d_in[1];
  const float* fc0_w = (const float*)d_in[2];
  const float* fc0_b = (const float*)d_in[3];
  const float* fc1_w = (const float*)d_in[4];
  const float* fc1_b = (const float*)d_in[5];
  const float* fc2_w = (const float*)d_in[6];
  const float* fc2_b = (const float*)d_in[7];
  const float* fc3_w = (const float*)d_in[8];
  const float* fc3_b = (const float*)d_in[9];
  const float* w_ih0 = (const float*)d_in[10];
  const float* w_hh0 = (const float*)d_in[11];
  const float* b_ih0 = (const float*)d_in[12];
  const float* b_hh0 = (const float*)d_in[13];
  const float* w_ih1 = (const float*)d_in[14];
  const float* w_hh1 = (const float*)d_in[15];
  const float* b_ih1 = (const float*)d_in[16];
  const float* b_hh1 = (const float*)d_in[17];
  float* out = (float*)d_out;
  float* ws  = (float*)d_ws;

  // ws layout (float offsets). Total ~73.8 MB.
  _Float16* preH = (_Float16*)ws;                    // [32768][512] fp16
  float* U = ws + 8388608;
  _Float16* h16 = (_Float16*)U;                      // RNN phase: [32768][512]
  _Float16* t0  = (_Float16*)U;                      // FC phase: [8192][1024]
  float* R2 = U + 4194304;
  _Float16* t1  = (_Float16*)R2;                     // [8192][1024]
  _Float16* zc  = (_Float16*)R2;                     // [8192][256]
  _Float16* f3  = (_Float16*)(R2 + 1048576);         // [8192][128]
  float* wbase = ws + 16777216;
  float4*   QW0   = (float4*)wbase;
  float4*   QW1   = (float4*)(wbase + 131072);
  _Float16* fc0h  = (_Float16*)(wbase + 262144);
  _Float16* fc1h  = (_Float16*)(wbase + 393216);
  _Float16* fc2h  = (_Float16*)(wbase + 917504);
  _Float16* fc3h  = (_Float16*)(wbase + 1441792);
  _Float16* wih0h = (_Float16*)(wbase + 1507328);
  _Float16* wih1h = (_Float16*)(wbase + 1540096);
  // Flags live in the fc0h weight region: dead during the RNN phase,
  // rewritten by cvt_w16 at the start of every replay. 256 u32 = 1 KB.
  unsigned int* flagsBase = (unsigned int*)fc0h;

  pack_whh_fp16<<<128, 256, 0, stream>>>(w_hh0, QW0);
  pack_whh_fp16<<<128, 256, 0, stream>>>(w_hh1, QW1);
  cvt_w16<<<1024, 256, 0, stream>>>(fc0_w, fc0h, 1024, 200, 256);
  cvt_w16<<<4096, 256, 0, stream>>>(fc1_w, fc1h, 1024, 1024, 1024);
  cvt_w16<<<4096, 256, 0, stream>>>(fc2_w, fc2h, 1024, 1024, 1024);
  cvt_w16<<<512, 256, 0, stream>>>(fc3_w, fc3h, 128, 1024, 1024);
  cvt_w16<<<256, 256, 0, stream>>>(w_ih0, wih0h, 512, 128, 128);
  cvt_w16<<<1024, 256, 0, stream>>>(w_ih1, wih1h, 512, 512, 512);

  const int CH = 8192;  // 32768 rows in 4 chunks
  for (int c = 0; c < 4; c++) {
    size_t row0 = (size_t)c * CH;
    fuzzy16<<<CH, 256, 0, stream>>>(x + row0 * 50, fp, zc, CH);
    gemm16<<<dim3(8, 64), 256, 0, stream>>>(zc, fc0h, fc0_b, nullptr, t0, CH, 1024, 256);
    gemm16<<<dim3(8, 64), 256, 0, stream>>>(t0, fc1h, fc1_b, nullptr, t1, CH, 1024, 1024);
    gemm16<<<dim3(8, 64), 256, 0, stream>>>(t1, fc2h, fc2_b, nullptr, t0, CH, 1024, 1024);
    gemm16<<<dim3(1, 64), 256, 0, stream>>>(t0, fc3h, fc3_b, nullptr, f3, CH, 128, 1024);
    gemm16<<<dim3(4, 64), 256, 0, stream>>>(f3, wih0h, b_ih0, b_hh0,
                                            preH + row0 * 512, CH, 512, 128);
  }

  // FC stack done -> fc0h region is dead; zero the flag area (both layers).
  hipMemsetAsync((void*)flagsBase, 0, 256 * sizeof(unsigned int), stream);

  // RNN layer 0: preH -> h16 (fp16, feeds layer-1 input projection)
  rnn_split_k<<<128, 512, 0, stream>>>(preH, QW0, nullptr, h16, flagsBase);
  // pre1 = h0 @ w_ih1^T + b_ih1 + b_hh1 (fp16 out into preH)
  gemm16<<<dim3(4, 256), 256, 0, stream>>>(h16, wih1h, b_ih1, b_hh1, preH, 32768, 512, 512);
  // RNN layer 1: preH -> final fp32 output (h16 reused as exchange buffer)
  rnn_split_k<<<128, 512, 0, stream>>>(preH, QW1, out, h16, flagsBase + 128);
}

// Round 2
// 2100.303 us; speedup vs baseline: 2.2272x; 2.2272x over previous
//
#include <hip/hip_runtime.h>
#include <hip/hip_fp16.h>
#include <cstddef>

// FDRNN: fuzzy -> FC(200->1024->1024->1024->128) -> 2-layer tanh RNN (H=512)
// B=64, S=512 -> 32768 rows.
//
// R7: R6 post-mortem: VGPR_Count=84 proved the float4 w[32] ARRAY was demoted
// to scratch (both R6 and, in hindsight, R5) -> per-CU L2-port bound; plus the
// cross-block L3 exchange cost ~3700 cyc/step. R7 reverts to 1 block/batch and
// makes ALL 64 j-groups resident with no arrays:
//   - 49 groups in NAMED f32x4 ext_vector registers (196 VGPR; mem2reg-safe)
//   - 15 groups in LDS (120 KB; + 2KB h double-buffer = 122 KB static)
//   - 0 streamed, 0 scratch, 1 barrier/step, fast tanh (exp2+rcp).
// 512-thread block -> 256 VGPR/wave cap (2 waves/SIMD x 256 = SIMD file), so
// 49 groups (196) + ~35 temps fits. Model ~2000-2800 cyc/step.

typedef _Float16 half8 __attribute__((ext_vector_type(8)));
typedef float f32x4 __attribute__((ext_vector_type(4)));
typedef float f32v4 __attribute__((ext_vector_type(4)));
typedef _Float16 v2h __attribute__((ext_vector_type(2)));

__device__ __forceinline__ void gld_lds16(const void* g, void* lds) {
  __builtin_amdgcn_global_load_lds(
      (const __attribute__((address_space(1))) unsigned int*)g,
      (__attribute__((address_space(3))) unsigned int*)lds, 16, 0, 0);
}

// ---------------- fuzzy (fp16 out, K padded 200->256) ----------------
__global__ void fuzzy16(const float* __restrict__ x, const float* __restrict__ fp,
                        _Float16* __restrict__ z, int nrows) {
  int idx = blockIdx.x * blockDim.x + threadIdx.x;
  if (idx >= nrows * 256) return;
  int r = idx >> 8;
  int f = idx & 255;
  float v = 0.f;
  if (f < 200) {
    int i = f % 50;
    float xv = x[r * 50 + i];
    float mu = fp[2 * f];
    float sg = fp[2 * f + 1];
    float d = xv - mu;
    v = expf(-(d * d) / sg);
  }
  z[idx] = (_Float16)v;
}

// ---------------- weight fp32 -> fp16 (with optional K zero-pad) -------------
__global__ void cvt_w16(const float* __restrict__ W, _Float16* __restrict__ O,
                        int rows, int kin, int kpad) {
  int idx = blockIdx.x * blockDim.x + threadIdx.x;
  if (idx >= rows * kpad) return;
  int r = idx / kpad;
  int k = idx - r * kpad;
  O[idx] = (k < kin) ? (_Float16)W[(size_t)r * kin + k] : (_Float16)0.f;
}

// ---------------- MFMA fp16 GEMM: C16[M][N] = A16[M][K] @ W16[N][K]^T + b ----
__global__ __launch_bounds__(256) void gemm16(
    const _Float16* __restrict__ A, const _Float16* __restrict__ W,
    const float* __restrict__ b1, const float* __restrict__ b2,
    _Float16* __restrict__ C, int M, int N, int K) {
  __shared__ _Float16 As[128 * 32];
  __shared__ _Float16 Bs[128 * 32];
  const int tid = threadIdx.x;
  const int bm = blockIdx.y * 128;
  const int bn = blockIdx.x * 128;
  const int lane = tid & 63;
  const int wv = tid >> 6;
  const int wm = (wv >> 1) * 64;
  const int wn = (wv & 1) * 64;
  const int frow = lane & 15;
  const int fk = (lane >> 4) * 8;

  const int srow = tid >> 2;
  const int scol = (tid & 3) * 16;  // bytes
  const char* gA = (const char*)(A + (size_t)(bm + srow) * K) + scol;
  const char* gB = (const char*)(W + (size_t)(bn + srow) * K) + scol;
  const size_t rowstep = (size_t)64 * K * 2;
  char* lA = (char*)As + tid * 16;
  char* lB = (char*)Bs + tid * 16;

  f32x4 acc[4][4] = {};

  for (int k0 = 0; k0 < K; k0 += 32) {
    gld_lds16(gA, lA);
    gld_lds16(gA + rowstep, lA + 4096);
    gld_lds16(gB, lB);
    gld_lds16(gB + rowstep, lB + 4096);
    gA += 64;
    gB += 64;
    __syncthreads();
    half8 af[4], bf[4];
#pragma unroll
    for (int i = 0; i < 4; i++) {
      af[i] = *(const half8*)(As + (wm + i * 16 + frow) * 32 + fk);
      bf[i] = *(const half8*)(Bs + (wn + i * 16 + frow) * 32 + fk);
    }
#pragma unroll
    for (int i = 0; i < 4; i++)
#pragma unroll
      for (int j = 0; j < 4; j++)
        acc[i][j] = __builtin_amdgcn_mfma_f32_16x16x32_f16(af[i], bf[j], acc[i][j], 0, 0, 0);
    __syncthreads();
  }

  float bias[4];
#pragma unroll
  for (int j = 0; j < 4; j++) {
    int col = bn + wn + j * 16 + frow;
    bias[j] = b1[col] + (b2 ? b2[col] : 0.f);
  }
  const int r0 = (lane >> 4) * 4;
#pragma unroll
  for (int i = 0; i < 4; i++) {
#pragma unroll
    for (int r = 0; r < 4; r++) {
      int row = bm + wm + i * 16 + r0 + r;
      _Float16* Cp = C + (size_t)row * N + bn + wn + frow;
#pragma unroll
      for (int j = 0; j < 4; j++)
        Cp[j * 16] = (_Float16)(acc[i][j][r] + bias[j]);
    }
  }
}

// ---------------- RNN weight pack (fp32 -> fp16, 16B groups) ----------------
// QW[j4*512 + o] = 8 fp16 = w_hh[o][8*j4 .. 8*j4+7]
__global__ void pack_whh_fp16(const float* __restrict__ W, float4* __restrict__ QW) {
  int idx = blockIdx.x * blockDim.x + threadIdx.x;
  if (idx >= 32768) return;
  int j4 = idx >> 9;
  int o = idx & 511;
  const float* src = W + (size_t)o * 512 + j4 * 8;
  __align__(16) __half2 p[4];
#pragma unroll
  for (int k = 0; k < 4; k++)
    p[k] = __halves2half2(__float2half(src[2 * k]), __float2half(src[2 * k + 1]));
  QW[idx] = *(const float4*)p;
}

__device__ __forceinline__ float dot2acc(float wbits, float hbits, float acc) {
#if __has_builtin(__builtin_amdgcn_fdot2)
  return __builtin_amdgcn_fdot2(__builtin_bit_cast(v2h, wbits),
                                __builtin_bit_cast(v2h, hbits), acc, false);
#else
  float2 wf = __half22float2(__builtin_bit_cast(__half2, wbits));
  float2 hf = __half22float2(__builtin_bit_cast(__half2, hbits));
  return fmaf(wf.x, hf.x, fmaf(wf.y, hf.y, acc));
#endif
}

// 49 register-resident j-groups, expanded as NAMED variables (no array ->
// no SROA/demotion hazard; R6's array went to scratch, VGPR_Count=84).
#define FOR_WREG(X) \
  X(0) X(1) X(2) X(3) X(4) X(5) X(6) X(7) X(8) X(9) \
  X(10) X(11) X(12) X(13) X(14) X(15) X(16) X(17) X(18) X(19) \
  X(20) X(21) X(22) X(23) X(24) X(25) X(26) X(27) X(28) X(29) \
  X(30) X(31) X(32) X(33) X(34) X(35) X(36) X(37) X(38) X(39) \
  X(40) X(41) X(42) X(43) X(44) X(45) X(46) X(47) X(48)

#define NLDSG 15  // LDS-resident groups (49..63), 15*8KB = 120KB

// ---------------- RNN: one block per batch, W fully resident -----------------
__global__ __launch_bounds__(512, 2) void rnn_resident2_k(
    const _Float16* __restrict__ pre,  // [512][512] per batch, biases folded
    const f32v4* __restrict__ QW,      // packed fp16 w_hh [64 grp][512 o]
    float* __restrict__ out32,         // nullable: final fp32 output
    _Float16* __restrict__ out16) {    // nullable: fp16 h for next-layer GEMM
  const int b = blockIdx.x;
  const int o = threadIdx.x;
  __shared__ f32v4 wlds[NLDSG][512];             // 120 KB
  __shared__ __align__(16) __half hbuf[2][512];  // 2 KB double-buffered h

  const f32v4* qro = QW + o;
#define DECLW(g) f32v4 w##g = qro[(g) << 9];
  FOR_WREG(DECLW)
#pragma unroll
  for (int g = 0; g < NLDSG; g++) wlds[g][o] = qro[(49 + g) << 9];

  hbuf[0][o] = __float2half(0.f);
  __syncthreads();

  const _Float16* preb = pre + (size_t)b * 262144;
  float* ob32 = out32 ? out32 + (size_t)b * 262144 : nullptr;
  _Float16* ob16 = out16 ? out16 + (size_t)b * 262144 : nullptr;

  _Float16 pcur = preb[o];  // t=0 pre, prefetched
  int p = 0;
  for (int t = 0; t < 512; t++) {
    const f32v4* hs4 = (const f32v4*)hbuf[p];
    float a0 = (float)pcur;
    float a1 = 0.f, a2 = 0.f, a3 = 0.f;
    if (t < 511) pcur = preb[(t + 1) * 512 + o];  // prefetch, used next iter

#define DOTW(g)                              \
  {                                          \
    f32v4 hq = hs4[g];                       \
    a0 = dot2acc(w##g.x, hq.x, a0);          \
    a1 = dot2acc(w##g.y, hq.y, a1);          \
    a2 = dot2acc(w##g.z, hq.z, a2);          \
    a3 = dot2acc(w##g.w, hq.w, a3);          \
  }
    FOR_WREG(DOTW)

#pragma unroll
    for (int g = 0; g < NLDSG; g++) {
      f32v4 q = wlds[g][o];
      f32v4 hq = hs4[49 + g];
      a0 = dot2acc(q.x, hq.x, a0);
      a1 = dot2acc(q.y, hq.y, a1);
      a2 = dot2acc(q.z, hq.z, a2);
      a3 = dot2acc(q.w, hq.w, a3);
    }
    float v = (a0 + a1) + (a2 + a3);
    // fast tanh: 1 - 2/(exp(2v)+1); exact at saturation, ~1e-6 rel error
    float z = __expf(2.f * v);
    float r = __builtin_amdgcn_rcpf(z + 1.f);
    float hn = fmaf(-2.f, r, 1.f);
    hbuf[p ^ 1][o] = __float2half(hn);
    if (ob32) ob32[t * 512 + o] = hn;
    if (ob16) ob16[t * 512 + o] = (_Float16)hn;
    p ^= 1;
    __syncthreads();  // writes to hbuf[p] visible before next step reads
  }
}

extern "C" void kernel_launch(void* const* d_in, const int* in_sizes, int n_in,
                              void* d_out, int out_size, void* d_ws, size_t ws_size,
                              hipStream_t stream) {
  const float* x     = (const float*)d_in[0];
  const float* fp    = (const float*)d_in[1];
  const float* fc0_w = (const float*)d_in[2];
  const float* fc0_b = (const float*)d_in[3];
  const float* fc1_w = (const float*)d_in[4];
  const float* fc1_b = (const float*)d_in[5];
  const float* fc2_w = (const float*)d_in[6];
  const float* fc2_b = (const float*)d_in[7];
  const float* fc3_w = (const float*)d_in[8];
  const float* fc3_b = (const float*)d_in[9];
  const float* w_ih0 = (const float*)d_in[10];
  const float* w_hh0 = (const float*)d_in[11];
  const float* b_ih0 = (const float*)d_in[12];
  const float* b_hh0 = (const float*)d_in[13];
  const float* w_ih1 = (const float*)d_in[14];
  const float* w_hh1 = (const float*)d_in[15];
  const float* b_ih1 = (const float*)d_in[16];
  const float* b_hh1 = (const float*)d_in[17];
  float* out = (float*)d_out;
  float* ws  = (float*)d_ws;

  // ws layout (float offsets). Total ~73.8 MB.
  _Float16* preH = (_Float16*)ws;                    // [32768][512] fp16
  float* U = ws + 8388608;
  _Float16* h16 = (_Float16*)U;                      // RNN phase: [32768][512]
  _Float16* t0  = (_Float16*)U;                      // FC phase: [8192][1024]
  float* R2 = U + 4194304;
  _Float16* t1  = (_Float16*)R2;                     // [8192][1024]
  _Float16* zc  = (_Float16*)R2;                     // [8192][256]
  _Float16* f3  = (_Float16*)(R2 + 1048576);         // [8192][128]
  float* wbase = ws + 16777216;
  float4*   QW0   = (float4*)wbase;
  float4*   QW1   = (float4*)(wbase + 131072);
  _Float16* fc0h  = (_Float16*)(wbase + 262144);
  _Float16* fc1h  = (_Float16*)(wbase + 393216);
  _Float16* fc2h  = (_Float16*)(wbase + 917504);
  _Float16* fc3h  = (_Float16*)(wbase + 1441792);
  _Float16* wih0h = (_Float16*)(wbase + 1507328);
  _Float16* wih1h = (_Float16*)(wbase + 1540096);

  pack_whh_fp16<<<128, 256, 0, stream>>>(w_hh0, QW0);
  pack_whh_fp16<<<128, 256, 0, stream>>>(w_hh1, QW1);
  cvt_w16<<<1024, 256, 0, stream>>>(fc0_w, fc0h, 1024, 200, 256);
  cvt_w16<<<4096, 256, 0, stream>>>(fc1_w, fc1h, 1024, 1024, 1024);
  cvt_w16<<<4096, 256, 0, stream>>>(fc2_w, fc2h, 1024, 1024, 1024);
  cvt_w16<<<512, 256, 0, stream>>>(fc3_w, fc3h, 128, 1024, 1024);
  cvt_w16<<<256, 256, 0, stream>>>(w_ih0, wih0h, 512, 128, 128);
  cvt_w16<<<1024, 256, 0, stream>>>(w_ih1, wih1h, 512, 512, 512);

  const int CH = 8192;  // 32768 rows in 4 chunks
  for (int c = 0; c < 4; c++) {
    size_t row0 = (size_t)c * CH;
    fuzzy16<<<CH, 256, 0, stream>>>(x + row0 * 50, fp, zc, CH);
    gemm16<<<dim3(8, 64), 256, 0, stream>>>(zc, fc0h, fc0_b, nullptr, t0, CH, 1024, 256);
    gemm16<<<dim3(8, 64), 256, 0, stream>>>(t0, fc1h, fc1_b, nullptr, t1, CH, 1024, 1024);
    gemm16<<<dim3(8, 64), 256, 0, stream>>>(t1, fc2h, fc2_b, nullptr, t0, CH, 1024, 1024);
    gemm16<<<dim3(1, 64), 256, 0, stream>>>(t0, fc3h, fc3_b, nullptr, f3, CH, 128, 1024);
    gemm16<<<dim3(4, 64), 256, 0, stream>>>(f3, wih0h, b_ih0, b_hh0,
                                            preH + row0 * 512, CH, 512, 128);
  }

  // RNN layer 0: preH -> h16 (fp16, feeds layer-1 input projection)
  rnn_resident2_k<<<64, 512, 0, stream>>>(preH, (const f32v4*)QW0, nullptr, h16);
  // pre1 = h0 @ w_ih1^T + b_ih1 + b_hh1 (fp16 out into preH)
  gemm16<<<dim3(4, 256), 256, 0, stream>>>(h16, wih1h, b_ih1, b_hh1, preH, 32768, 512, 512);
  // RNN layer 1: preH -> final fp32 output
  rnn_resident2_k<<<64, 512, 0, stream>>>(preH, (const f32v4*)QW1, out, nullptr);
}